// Round 6
// baseline (138.906 us; speedup 1.0000x reference)
//
#include <hip/hip_runtime.h>
#include <hip/hip_bf16.h>

#define NB 4
#define NQ 4096
#define CI 256
#define CO 256
#define NS 8
#define HFEAT 128
#define WFEAT 128
#define NPIX (HFEAT * WFEAT)

typedef short bf16x8 __attribute__((ext_vector_type(8)));
typedef float f32x4 __attribute__((ext_vector_type(4)));

__device__ __forceinline__ unsigned short f2b(float x) {
    union { float f; unsigned u; } v; v.f = x;
    unsigned r = v.u + 0x7fff + ((v.u >> 16) & 1);
    return (unsigned short)(r >> 16);
}
__device__ __forceinline__ float b2f(unsigned short x) {
    union { unsigned u; float f; } v; v.u = ((unsigned)x) << 16;
    return v.f;
}
__device__ __forceinline__ void b2f2(unsigned u, float& a, float& b) {
    union { unsigned x; float f; } va, vb;
    va.x = u << 16;
    vb.x = u & 0xffff0000u;
    a = va.f; b = vb.f;
}
// pack 2 fp32 -> dword of 2 bf16 (lo=a, hi=b), RNE. gfx950-verified (m214v22).
__device__ __forceinline__ unsigned cvtpk(float a, float b) {
    unsigned r;
    asm("v_cvt_pk_bf16_f32 %0, %1, %2" : "=v"(r) : "v"(a), "v"(b));
    return r;
}
__device__ __forceinline__ void gload16(const void* g, void* l) {
    __builtin_amdgcn_global_load_lds((const __attribute__((address_space(1))) void*)g,
                                     (__attribute__((address_space(3))) void*)l, 16, 0, 0);
}

// ---------------------------------------------------------------------------
// Weight prep: Wk, Wv are [o][c] -> bf16 copy. Wq, Wo are [c][o] -> bf16 [o][c].
__global__ __launch_bounds__(256) void k_prep_w(const float* __restrict__ Wk,
                                                const float* __restrict__ Wv,
                                                const float* __restrict__ Wq,
                                                const float* __restrict__ Wo,
                                                unsigned short* __restrict__ out) {
    int mat = blockIdx.y;
    int base = blockIdx.x * 1024 + threadIdx.x * 4;
    const float* src = (mat == 0) ? Wk : (mat == 1) ? Wv : (mat == 2) ? Wq : Wo;
    unsigned short* dst = out + (size_t)mat * 65536;
    if (mat < 2) {
#pragma unroll
        for (int i = 0; i < 4; ++i) dst[base + i] = f2b(src[base + i]);
    } else {
#pragma unroll
        for (int i = 0; i < 4; ++i) {
            int oi = base + i;
            int o = oi >> 8, c = oi & 255;
            dst[oi] = f2b(src[c * 256 + o]);  // transpose
        }
    }
}

// ---------------------------------------------------------------------------
// queries fp32 -> bf16
__global__ __launch_bounds__(256) void k_cvt(const float* __restrict__ in,
                                             unsigned short* __restrict__ out) {
    size_t i = ((size_t)blockIdx.x * 256 + threadIdx.x) * 8;
    float4 a = *reinterpret_cast<const float4*>(in + i);
    float4 b = *reinterpret_cast<const float4*>(in + i + 4);
    union { uint2 u2[2]; unsigned short h[8]; } pk;
    pk.h[0] = f2b(a.x); pk.h[1] = f2b(a.y); pk.h[2] = f2b(a.z); pk.h[3] = f2b(a.w);
    pk.h[4] = f2b(b.x); pk.h[5] = f2b(b.y); pk.h[6] = f2b(b.z); pk.h[7] = f2b(b.w);
    *reinterpret_cast<uint4*>(out + i) = *reinterpret_cast<uint4*>(&pk);
}

// ---------------------------------------------------------------------------
// loc = tanh(q @ Wl + bl). 32 rows/block; q rows + Wl^T staged in LDS.
__global__ __launch_bounds__(256) void k_loc(const float* __restrict__ q,
                                             const float* __restrict__ Wl,
                                             const float* __restrict__ bl,
                                             float* __restrict__ loc) {
    __shared__ float qs[32][260];
    __shared__ float wlt[16][260];
    int t = threadIdx.x;
    int row0 = blockIdx.x * 32;
    {
        int rr = t >> 6;
        int c4 = (t & 63) * 4;
#pragma unroll
        for (int i = 0; i < 8; ++i) {
            int r = i * 4 + rr;
            *reinterpret_cast<float4*>(&qs[r][c4]) =
                *reinterpret_cast<const float4*>(q + (size_t)(row0 + r) * CI + c4);
        }
    }
    {
        int c = t;
#pragma unroll
        for (int col = 0; col < 16; ++col) wlt[col][c] = Wl[c * 16 + col];
    }
    __syncthreads();
    int r = t & 31;
    int cg = t >> 5;
    float a0 = bl[cg], a1 = bl[cg + 8];
    for (int c4 = 0; c4 < 256; c4 += 4) {
        float4 qv = *reinterpret_cast<const float4*>(&qs[r][c4]);
        float4 w0 = *reinterpret_cast<const float4*>(&wlt[cg][c4]);
        float4 w1 = *reinterpret_cast<const float4*>(&wlt[cg + 8][c4]);
        a0 = fmaf(qv.x, w0.x, a0); a0 = fmaf(qv.y, w0.y, a0);
        a0 = fmaf(qv.z, w0.z, a0); a0 = fmaf(qv.w, w0.w, a0);
        a1 = fmaf(qv.x, w1.x, a1); a1 = fmaf(qv.y, w1.y, a1);
        a1 = fmaf(qv.z, w1.z, a1); a1 = fmaf(qv.w, w1.w, a1);
    }
    loc[(size_t)(row0 + r) * 16 + cg] = tanhf(a0);
    loc[(size_t)(row0 + r) * 16 + cg + 8] = tanhf(a1);
}

// ---------------------------------------------------------------------------
// MFMA GEMM (m97 structure): C[M][256] = A[M][256] * Bt[256][256]^T + bias
template <int OUT_BF16>
__global__ __launch_bounds__(256) void k_gemm(const unsigned short* __restrict__ A,
                                              const unsigned short* __restrict__ Bt,
                                              const float* __restrict__ bias,
                                              void* __restrict__ outp) {
    __shared__ unsigned short As[128][32];
    __shared__ unsigned short Bs[128][32];
    int t = threadIdx.x;
    int w = t >> 6, l = t & 63;
    int bm = blockIdx.x >> 1, bc = blockIdx.x & 1;
    int m0 = bm * 128, n0 = bc * 128;
    int wr = w >> 1, wc = w & 1;

    f32x4 acc[4][4];
#pragma unroll
    for (int n = 0; n < 4; ++n) {
        float bv = bias[n0 + wc * 64 + n * 16 + (l & 15)];
#pragma unroll
        for (int m = 0; m < 4; ++m) acc[m][n] = f32x4{bv, bv, bv, bv};
    }

    int ar = wr * 64 + (l & 15);
    int br = wc * 64 + (l & 15);
    int kq = (l >> 4) * 8;
    int srow = (l >> 2);
    int scol = (l & 3) * 8;

    for (int kk = 0; kk < 8; ++kk) {
        int k0 = kk * 32;
#pragma unroll
        for (int j = 0; j < 2; ++j) {
            int row = w * 32 + j * 16 + srow;
            gload16(A + (size_t)(m0 + row) * CI + k0 + scol, &As[w * 32 + j * 16][0]);
            gload16(Bt + (size_t)(n0 + row) * CI + k0 + scol, &Bs[w * 32 + j * 16][0]);
        }
        __syncthreads();
        bf16x8 af[4], bfr[4];
#pragma unroll
        for (int m = 0; m < 4; ++m) af[m] = *reinterpret_cast<const bf16x8*>(&As[ar + m * 16][kq]);
#pragma unroll
        for (int n = 0; n < 4; ++n) bfr[n] = *reinterpret_cast<const bf16x8*>(&Bs[br + n * 16][kq]);
#pragma unroll
        for (int m = 0; m < 4; ++m)
#pragma unroll
            for (int n = 0; n < 4; ++n)
                acc[m][n] = __builtin_amdgcn_mfma_f32_16x16x32_bf16(af[m], bfr[n], acc[m][n], 0, 0, 0);
        __syncthreads();
    }

    int rbase = m0 + wr * 64 + (l >> 4) * 4;
    int cbase = n0 + wc * 64 + (l & 15);
#pragma unroll
    for (int m = 0; m < 4; ++m)
#pragma unroll
        for (int n = 0; n < 4; ++n)
#pragma unroll
            for (int r = 0; r < 4; ++r) {
                size_t row = rbase + m * 16 + r;
                size_t col = cbase + n * 16;
                if (OUT_BF16)
                    ((unsigned short*)outp)[row * CO + col] = f2b(acc[m][n][r]);
                else
                    ((float*)outp)[row * CO + col] = acc[m][n][r];
            }
}

// ---------------------------------------------------------------------------
// Fused 1x1-conv projection v3: ONE-SHOT staging. Whole K=256 for A (128 px)
// and B (128-o half) in LDS; inner loop = pure ds_read+MFMA, no barriers.
// A: scalar fp32 loads (pixels strided 32 per thread -> conflict-free-ish
// writes), cvt_pk to bf16 pairs, 1-bit XOR col swizzle (both sides).
// B: gload16 linear dest + inverse-permuted global source (blk ^ row&7),
// same XOR on read. 3 barriers per block; A fetched from HBM exactly once.
__global__ __launch_bounds__(256, 1) void k_proj(const float* __restrict__ keys,
                                                 const float* __restrict__ values,
                                                 const unsigned short* __restrict__ wbuf,
                                                 const float* __restrict__ bK,
                                                 const float* __restrict__ bV,
                                                 unsigned short* __restrict__ kp,
                                                 unsigned short* __restrict__ vp) {
    __shared__ unsigned short As[128][264];   // 66 KB, pitch 132 dwords (16B-aligned rows)
    __shared__ unsigned short Bs[128][256];   // 64 KB, one 128-o half at a time

    int bid = blockIdx.x;          // 1024 blocks: map(2) x batch(4) x pixtile(128)
    int map = bid >> 9;
    int b = (bid >> 7) & 3;
    int tile = bid & 127;
    int pix0 = tile << 7;

    const float* X = (map ? values : keys) + (size_t)b * (CI * NPIX);
    const unsigned short* W = wbuf + (size_t)map * 65536;
    const float* bias = map ? bV : bK;
    unsigned short* outp = (map ? vp : kp) + (size_t)b * (NPIX * CO);

    int t = threadIdx.x;
    int w = t >> 6, l = t & 63;
    int wr = w >> 1, wc = w & 1;

    // ---- B staging: 16 gload16/wave covering 128 rows x 256 ch ----
#define STAGEB(o0h)                                                          \
    {                                                                        \
        _Pragma("unroll")                                                    \
        for (int j = 0; j < 16; ++j) {                                       \
            int row0_ = w * 32 + 2 * j;                                      \
            int rowl_ = row0_ + (l >> 5);                                    \
            const unsigned short* src_ =                                     \
                W + (size_t)((o0h) + rowl_) * CI + (((l & 31) ^ (rowl_ & 7)) << 3); \
            gload16(src_, &Bs[row0_][0]);                                    \
        }                                                                    \
    }

    // ---- A staging geometry ----
    int px = t & 31;          // pixel lane; thread owns px, px+32, px+64, px+96
    int cg = t >> 5;          // channel group 0..7
    int swA = ((px >> 3) & 1) << 2;   // dword-col bit2 XOR (write side)
    const float* Xb = X + pix0 + px;

    float bufA[32], bufB[32];

#define LOADC(buf, chunk)                                                    \
    {                                                                        \
        _Pragma("unroll")                                                    \
        for (int cc = 0; cc < 8; ++cc) {                                     \
            const float* p_ = Xb + (size_t)((chunk)*64 + cg * 8 + cc) * NPIX;\
            _Pragma("unroll")                                                \
            for (int w4 = 0; w4 < 4; ++w4) buf[cc * 4 + w4] = p_[w4 * 32];   \
        }                                                                    \
    }
#define WRITEC(buf, chunk)                                                   \
    {                                                                        \
        _Pragma("unroll")                                                    \
        for (int c2 = 0; c2 < 4; ++c2) {                                     \
            _Pragma("unroll")                                                \
            for (int w4 = 0; w4 < 4; ++w4) {                                 \
                unsigned d_ = cvtpk(buf[(2 * c2) * 4 + w4], buf[(2 * c2 + 1) * 4 + w4]); \
                ((unsigned*)&As[px + 32 * w4][0])[((chunk)*32 + cg * 4 + c2) ^ swA] = d_; \
            }                                                                \
        }                                                                    \
    }

    STAGEB(0);
    LOADC(bufA, 0);
    LOADC(bufB, 1);
    WRITEC(bufA, 0);
    LOADC(bufA, 2);
    WRITEC(bufB, 1);
    LOADC(bufB, 3);
    WRITEC(bufA, 2);
    WRITEC(bufB, 3);
    __syncthreads();   // drains A ds_writes + B0 DMA (vmcnt0 before barrier)

    // ---- compute geometry ----
    int ar = wr * 64 + (l & 15);
    int br = wc * 64 + (l & 15);
    int g = l >> 4;
    int aswS = ((l >> 3) & 1) << 3;   // shorts-col bit3 XOR (read side of As)

    f32x4 acc[4][4];

#define INITACC(o0h)                                                         \
    {                                                                        \
        _Pragma("unroll")                                                    \
        for (int n = 0; n < 4; ++n) {                                        \
            float bv_ = bias[(o0h) + wc * 64 + n * 16 + (l & 15)];           \
            _Pragma("unroll")                                                \
            for (int m = 0; m < 4; ++m) acc[m][n] = f32x4{bv_, bv_, bv_, bv_}; \
        }                                                                    \
    }
#define COMPUTE()                                                            \
    {                                                                        \
        _Pragma("unroll")                                                    \
        for (int kk = 0; kk < 8; ++kk) {                                     \
            bf16x8 af[4], bfr[4];                                            \
            _Pragma("unroll")                                                \
            for (int m = 0; m < 4; ++m)                                      \
                af[m] = *reinterpret_cast<const bf16x8*>(                    \
                    &As[ar + m * 16][(kk * 32 + g * 8) ^ aswS]);             \
            _Pragma("unroll")                                                \
            for (int n = 0; n < 4; ++n)                                      \
                bfr[n] = *reinterpret_cast<const bf16x8*>(                   \
                    &Bs[br + n * 16][((kk * 4 + g) ^ (l & 7)) << 3]);        \
            _Pragma("unroll")                                                \
            for (int m = 0; m < 4; ++m)                                      \
                _Pragma("unroll")                                            \
                for (int n = 0; n < 4; ++n)                                  \
                    acc[m][n] = __builtin_amdgcn_mfma_f32_16x16x32_bf16(     \
                        af[m], bfr[n], acc[m][n], 0, 0, 0);                  \
        }                                                                    \
    }
#define STOREC(o0h)                                                          \
    {                                                                        \
        int rb_ = wr * 64 + (l >> 4) * 4;                                    \
        int cb_ = (o0h) + wc * 64 + (l & 15);                                \
        _Pragma("unroll")                                                    \
        for (int m = 0; m < 4; ++m)                                          \
            _Pragma("unroll")                                                \
            for (int n = 0; n < 4; ++n)                                      \
                _Pragma("unroll")                                            \
                for (int r = 0; r < 4; ++r)                                  \
                    outp[(size_t)(pix0 + rb_ + m * 16 + r) * CO + cb_ + n * 16] = \
                        f2b(acc[m][n][r]);                                   \
    }

    INITACC(0);
    COMPUTE();
    __syncthreads();   // all waves done reading Bs half 0
    STAGEB(128);       // DMA half 1 while we store C half 0
    STOREC(0);
    INITACC(128);
    __syncthreads();   // drains B1 DMA + C0 stores
    COMPUTE();
    STOREC(128);

#undef STAGEB
#undef LOADC
#undef WRITEC
#undef INITACC
#undef COMPUTE
#undef STOREC
}

// ---------------------------------------------------------------------------
// Deformable sampling + attention. One wave per query, 4 ch/lane (uint2 loads).
// XCD-batch clustering: XCD pair {2b,2b+1} owns batch b (L2 locality on maps).
__global__ __launch_bounds__(256) void k_attn(const unsigned short* __restrict__ kp,
                                              const unsigned short* __restrict__ vp,
                                              const unsigned short* __restrict__ qh,
                                              const float* __restrict__ loc,
                                              unsigned short* __restrict__ aout) {
    int t = threadIdx.x;
    int wv = t >> 6, l = t & 63;
    int blk = blockIdx.x;
    int xcd = blk & 7;
    int b = xcd >> 1;
    int idx = ((blk >> 3) << 1) | (xcd & 1);
    int bq = (b << 12) | (idx << 2) | wv;

    float qv[4];
    {
        uint2 qr = *reinterpret_cast<const uint2*>(qh + (size_t)bq * CO + l * 4);
        b2f2(qr.x, qv[0], qv[1]);
        b2f2(qr.y, qv[2], qv[3]);
    }
    const unsigned short* kb = kp + (size_t)b * NPIX * CO;
    const unsigned short* vb = vp + (size_t)b * NPIX * CO;
    const float* lq = loc + (size_t)bq * (NS * 2);
    int choff = l * 4;

    float m = -3.0e38f, lsum = 0.f;
    float o0 = 0.f, o1 = 0.f, o2 = 0.f, o3 = 0.f;

#pragma unroll
    for (int s = 0; s < NS; ++s) {
        float x = lq[2 * s];
        float y = lq[2 * s + 1];
        float gx = (x + 1.f) * (WFEAT * 0.5f) - 0.5f;
        float gy = (y + 1.f) * (HFEAT * 0.5f) - 0.5f;
        float x0f = floorf(gx), y0f = floorf(gy);
        int x0 = (int)x0f, y0 = (int)y0f;
        float wx1 = gx - x0f, wy1 = gy - y0f;
        float wx0 = 1.f - wx1, wy0 = 1.f - wy1;
        bool xa = (x0 >= 0) && (x0 < WFEAT);
        bool xb = (x0 + 1 >= 0) && (x0 + 1 < WFEAT);
        bool ya = (y0 >= 0) && (y0 < HFEAT);
        bool yb = (y0 + 1 >= 0) && (y0 + 1 < HFEAT);
        size_t i00 = (size_t)(y0 * WFEAT + x0) * CO + choff;

        uint2 z = make_uint2(0u, 0u);
        uint2 k00 = z, k01 = z, k10 = z, k11 = z;
        uint2 v00 = z, v01 = z, v10 = z, v11 = z;
        if (xa && ya) { k00 = *(const uint2*)(kb + i00);                 v00 = *(const uint2*)(vb + i00); }
        if (xb && ya) { k01 = *(const uint2*)(kb + i00 + CO);            v01 = *(const uint2*)(vb + i00 + CO); }
        if (xa && yb) { k10 = *(const uint2*)(kb + i00 + WFEAT * CO);    v10 = *(const uint2*)(vb + i00 + WFEAT * CO); }
        if (xb && yb) { k11 = *(const uint2*)(kb + i00 + (WFEAT+1)*CO);  v11 = *(const uint2*)(vb + i00 + (WFEAT+1)*CO); }

        float a0, a1, b0, b1, c0, c1, d0, d1;
        float ks[4], vs[4];
        b2f2(k00.x, a0, a1); b2f2(k01.x, b0, b1); b2f2(k10.x, c0, c1); b2f2(k11.x, d0, d1);
        ks[0] = fmaf(fmaf(b0, wx1, a0 * wx0), wy0, fmaf(d0, wx1, c0 * wx0) * wy1);
        ks[1] = fmaf(fmaf(b1, wx1, a1 * wx0), wy0, fmaf(d1, wx1, c1 * wx0) * wy1);
        b2f2(k00.y, a0, a1); b2f2(k01.y, b0, b1); b2f2(k10.y, c0, c1); b2f2(k11.y, d0, d1);
        ks[2] = fmaf(fmaf(b0, wx1, a0 * wx0), wy0, fmaf(d0, wx1, c0 * wx0) * wy1);
        ks[3] = fmaf(fmaf(b1, wx1, a1 * wx0), wy0, fmaf(d1, wx1, c1 * wx0) * wy1);
        b2f2(v00.x, a0, a1); b2f2(v01.x, b0, b1); b2f2(v10.x, c0, c1); b2f2(v11.x, d0, d1);
        vs[0] = fmaf(fmaf(b0, wx1, a0 * wx0), wy0, fmaf(d0, wx1, c0 * wx0) * wy1);
        vs[1] = fmaf(fmaf(b1, wx1, a1 * wx0), wy0, fmaf(d1, wx1, c1 * wx0) * wy1);
        b2f2(v00.y, a0, a1); b2f2(v01.y, b0, b1); b2f2(v10.y, c0, c1); b2f2(v11.y, d0, d1);
        vs[2] = fmaf(fmaf(b0, wx1, a0 * wx0), wy0, fmaf(d0, wx1, c0 * wx0) * wy1);
        vs[3] = fmaf(fmaf(b1, wx1, a1 * wx0), wy0, fmaf(d1, wx1, c1 * wx0) * wy1);

        float p = fmaf(qv[0], ks[0], fmaf(qv[1], ks[1], fmaf(qv[2], ks[2], qv[3] * ks[3])));
        p += __shfl_xor(p, 1);
        p += __shfl_xor(p, 2);
        p += __shfl_xor(p, 4);
        float lg = p * 0.0625f;

        float nm = fmaxf(m, lg);
        float sc = __expf(m - nm);
        float wgt = __expf(lg - nm);
        lsum = fmaf(lsum, sc, wgt);
        o0 = fmaf(o0, sc, wgt * vs[0]);
        o1 = fmaf(o1, sc, wgt * vs[1]);
        o2 = fmaf(o2, sc, wgt * vs[2]);
        o3 = fmaf(o3, sc, wgt * vs[3]);
        m = nm;
    }

    float inv = 1.f / lsum;
    uint2 pk;
    pk.x = ((unsigned)f2b(o0 * inv)) | (((unsigned)f2b(o1 * inv)) << 16);
    pk.y = ((unsigned)f2b(o2 * inv)) | (((unsigned)f2b(o3 * inv)) << 16);
    *reinterpret_cast<uint2*>(aout + (size_t)bq * CO + choff) = pk;
}

// ---------------------------------------------------------------------------
extern "C" void kernel_launch(void* const* d_in, const int* in_sizes, int n_in,
                              void* d_out, int out_size, void* d_ws, size_t ws_size,
                              hipStream_t stream) {
    (void)in_sizes; (void)n_in; (void)out_size; (void)ws_size;
    const float* queries = (const float*)d_in[0];
    const float* keys    = (const float*)d_in[1];
    const float* values  = (const float*)d_in[2];
    const float* W_loc   = (const float*)d_in[3];
    const float* b_loc   = (const float*)d_in[4];
    const float* W_q     = (const float*)d_in[5];
    const float* b_q     = (const float*)d_in[6];
    const float* W_k     = (const float*)d_in[7];
    const float* b_k     = (const float*)d_in[8];
    const float* W_v     = (const float*)d_in[9];
    const float* b_v     = (const float*)d_in[10];
    const float* W_o     = (const float*)d_in[11];
    const float* b_o     = (const float*)d_in[12];
    float* out = (float*)d_out;

    char* ws = (char*)d_ws;
    unsigned short* kp   = (unsigned short*)(ws);                  // 32 MB
    unsigned short* vp   = (unsigned short*)(ws + 33554432);       // 32 MB
    unsigned short* qbf  = (unsigned short*)(ws + 67108864);       // 8 MB
    unsigned short* aout = (unsigned short*)(ws + 67108864);       // reuses qbf (dead by k_attn)
    unsigned short* qh   = (unsigned short*)(ws + 75497472);       // 8 MB
    float* locb          = (float*)(ws + 83886080);                // 1 MB
    unsigned short* wbuf = (unsigned short*)(ws + 84934656);       // 512 KB

    k_prep_w<<<dim3(64, 4), 256, 0, stream>>>(W_k, W_v, W_q, W_o, wbuf);
    k_cvt<<<dim3(2048), 256, 0, stream>>>(queries, qbf);
    k_loc<<<dim3(512), 256, 0, stream>>>(queries, W_loc, b_loc, locb);
    k_gemm<1><<<dim3(256), 256, 0, stream>>>(qbf, wbuf + 131072, b_q, qh);
    k_proj<<<dim3(1024), 256, 0, stream>>>(keys, values, wbuf, b_k, b_v, kp, vp);
    k_attn<<<dim3(NB * NQ / 4), 256, 0, stream>>>(kp, vp, qh, locb, aout);
    k_gemm<0><<<dim3(256), 256, 0, stream>>>(aout, wbuf + 196608, b_o, out);
}